// Round 12
// baseline (240.020 us; speedup 1.0000x reference)
//
#include <hip/hip_runtime.h>
#include <hip/hip_bf16.h>
#include <cfloat>

#define B 4
#define NC 2048
#define NF 8192
#define CIN 128
#define CH 64
#define COUT 128
#define EC 16384
#define EF 65536
#define ZB 256          // z-sort bins
#define LDK 40

typedef __attribute__((ext_vector_type(8))) short short8v;
typedef __attribute__((ext_vector_type(4))) float f32x4;

__device__ __forceinline__ ushort f2b(float v) {
    __hip_bfloat16 h = __float2bfloat16(v);
    return *reinterpret_cast<ushort*>(&h);
}
__device__ __forceinline__ float b2f(ushort u) {
    __hip_bfloat16 h = *reinterpret_cast<__hip_bfloat16*>(&u);
    return __bfloat162float(h);
}

// ---------------------------------------------------------------- combined prep: hists / z-bins / weight transposes / conversions
__global__ void count_all(const int* __restrict__ ec, const int* __restrict__ ef,
                          const int* __restrict__ mask, const float* __restrict__ pos,
                          int* __restrict__ cntC, int* __restrict__ cntF, int* __restrict__ cntZ,
                          int* __restrict__ inv,
                          const float* __restrict__ W2e, const float* __restrict__ W2n,
                          const float* __restrict__ Wse, const float* __restrict__ Wsn,
                          ushort* __restrict__ W2eT, ushort* __restrict__ W2nT,
                          ushort* __restrict__ WseT, ushort* __restrict__ WsnT,
                          const float* __restrict__ W1e, const float* __restrict__ W1n,
                          ushort* __restrict__ W1eT, ushort* __restrict__ W1nT,
                          const float* __restrict__ x, ushort* __restrict__ xb16) {
    const int b = blockIdx.y, z = blockIdx.z;
    const int i = blockIdx.x * 256 + threadIdx.x;
    if (z == 0) {
        if (i < EC) atomicAdd(&cntC[b * NC + ec[(size_t)b * 2 * EC + EC + i]], 1);
    } else if (z == 1) {
        if (i < EF) atomicAdd(&cntF[b * NF + ef[(size_t)b * 2 * EF + EF + i]], 1);
        if (i < NF) inv[(size_t)b * NF + i] = -1;
    } else if (z == 2) {
        if (i < NC) {
            int m = mask[b * NC + i];
            float pz = pos[((size_t)b * NF + m) * 3 + 2];
            int zb = min(max((int)(pz * (float)ZB), 0), ZB - 1);
            atomicAdd(&cntZ[b * ZB + zb], 1);
        }
    } else if (z == 3) {   // fine weight transposes, b selects matrix
        const float* src; ushort* dst; int K2;
        switch (b) {
            case 0: src = W2e; dst = W2eT; K2 = 128; break;
            case 1: src = W2n; dst = W2nT; K2 = 192; break;
            case 2: src = Wse; dst = WseT; K2 = 256; break;
            default: src = Wsn; dst = WsnT; K2 = 256; break;
        }
        if (i < K2 * 128) {
            int n = i & 127, k = i >> 7;
            dst[(size_t)n * K2 + k] = f2b(src[i]);
        }
    } else if (z == 4) {   // coarse weight transposes
        if (b == 0) {
            if (i < 128 * 128) {   // W1eT[n][k]: n<64 -> P (W1e rows 0-127), n>=64 -> Q (rows 128-255)
                int n = i >> 7, k = i & 127;
                W1eT[i] = f2b(W1e[(size_t)(k + ((n >> 6) << 7)) * 64 + (n & 63)]);
            }
        } else if (b == 1) {
            if (i < 64 * 192) {    // W1nT[n][k] = W1n[k][n]
                int n = i / 192, k = i - n * 192;
                W1nT[i] = f2b(W1n[(size_t)k * 64 + n]);
            }
        }
    } else {               // z == 5: x -> bf16 (per graph b)
        for (int j = i; j < NC * CIN; j += (EF / 256) * 256)
            xb16[(size_t)b * NC * CIN + j] = f2b(x[(size_t)b * NC * CIN + j]);
    }
}

// ---------------------------------------------------------------- combined exclusive scan (grid = 3*B blocks)
template<int N, int OSTR, bool EXTRA>
__device__ __forceinline__ void scan_body(const int* __restrict__ cnt, int* __restrict__ offs,
                                          int* __restrict__ cur, int b, int* part) {
    const int tid = threadIdx.x;
    constexpr int PER = (N + 1023) / 1024;
    int local[PER];
    int s = 0;
    #pragma unroll
    for (int i = 0; i < PER; ++i) {
        int id = tid * PER + i;
        local[i] = s;
        if (id < N) s += cnt[b * N + id];
    }
    part[tid] = s;
    __syncthreads();
    for (int off = 1; off < 1024; off <<= 1) {
        int v = (tid >= off) ? part[tid - off] : 0;
        __syncthreads();
        part[tid] += v;
        __syncthreads();
    }
    int pre = tid ? part[tid - 1] : 0;
    #pragma unroll
    for (int i = 0; i < PER; ++i) {
        int id = tid * PER + i;
        if (id < N) {
            int o = pre + local[i];
            offs[b * OSTR + id] = o;
            cur[b * OSTR + id] = o;
        }
    }
    if (EXTRA && tid == 1023) offs[b * OSTR + N] = part[1023];
}

__global__ __launch_bounds__(1024) void scan_all(
    const int* __restrict__ cntC, int* __restrict__ offC, int* __restrict__ curC,
    const int* __restrict__ cntF, int* __restrict__ offF, int* __restrict__ curF,
    const int* __restrict__ cntZ, int* __restrict__ offZ, int* __restrict__ curZ) {
    __shared__ int part[1024];
    const int cfg = blockIdx.x >> 2;   // B == 4
    const int b = blockIdx.x & 3;
    if (cfg == 0)      scan_body<NC, NC, false>(cntC, offC, curC, b, part);
    else if (cfg == 1) scan_body<NF, NF, false>(cntF, offF, curF, b, part);
    else               scan_body<ZB, ZB + 1, true>(cntZ, offZ, curZ, b, part);
}

// ---------------------------------------------------------------- combined fill: CSRs / z-sorted coarse positions + inv map
__global__ void fill_all(const int* __restrict__ ec, const int* __restrict__ ef,
                         const int* __restrict__ mask, const float* __restrict__ pos,
                         int* __restrict__ curC, int* __restrict__ curF, int* __restrict__ curZ,
                         int* __restrict__ csrC, int* __restrict__ csrF,
                         float4* __restrict__ sposg, int* __restrict__ inv) {
    const int b = blockIdx.y, z = blockIdx.z;
    const int i = blockIdx.x * 256 + threadIdx.x;
    if (z == 0) {
        if (i < EC) {
            const int* eb = ec + (size_t)b * 2 * EC;
            int src = eb[i], dst = eb[EC + i];
            int p = atomicAdd(&curC[b * NC + dst], 1);
            csrC[(size_t)b * EC + p] = src;
        }
    } else if (z == 1) {
        if (i < EF) {
            const int* eb = ef + (size_t)b * 2 * EF;
            int src = eb[i], dst = eb[EF + i];
            int p = atomicAdd(&curF[b * NF + dst], 1);
            csrF[(size_t)b * EF + p] = src;
        }
    } else {
        if (i < NC) {
            int m = mask[b * NC + i];
            const float* p = pos + ((size_t)b * NF + m) * 3;
            float px = p[0], py = p[1], pz = p[2];
            int zb = min(max((int)(pz * (float)ZB), 0), ZB - 1);
            int slot = atomicAdd(&curZ[b * (ZB + 1) + zb], 1);
            sposg[(size_t)b * NC + slot] = make_float4(px, py, pz, __int_as_float(i));
            inv[(size_t)b * NF + m] = b * NC + i;
        }
    }
}

// ---------------------------------------------------------------- top-3 helpers
__device__ __forceinline__ void ins3(float d, int c, float& d0, float& d1, float& d2,
                                     int& i0, int& i1, int& i2) {
    bool lt0 = d < d0, lt1 = d < d1, lt2 = d < d2;
    d2 = lt1 ? d1 : (lt2 ? d : d2);  i2 = lt1 ? i1 : (lt2 ? c : i2);
    d1 = lt0 ? d0 : (lt1 ? d : d1);  i1 = lt0 ? i0 : (lt1 ? c : i1);
    d0 = lt0 ? d  : d0;              i0 = lt0 ? c  : i0;
}
__device__ __forceinline__ void merge32(float& d0, float& d1, float& d2,
                                        int& i0, int& i1, int& i2) {
    #pragma unroll
    for (int off = 1; off <= 16; off <<= 1) {
        float od[3]; int oi[3];
        od[0] = __shfl_xor(d0, off); oi[0] = __shfl_xor(i0, off);
        od[1] = __shfl_xor(d1, off); oi[1] = __shfl_xor(i1, off);
        od[2] = __shfl_xor(d2, off); oi[2] = __shfl_xor(i2, off);
        #pragma unroll
        for (int j = 0; j < 3; ++j) ins3(od[j], oi[j], d0, d1, d2, i0, i1, i2);
    }
}

// ---------------------------------------------------------------- MFMA staged-segment inner loop (128-row tile)
__device__ __forceinline__ void mfma_seg(const ushort* __restrict__ Ab, int K, int m0,
                                         const ushort* __restrict__ Wt, int ldW, int wcol0,
                                         ushort* As, ushort* Wsm,
                                         int t, int wr, int wc, int fr, int fq,
                                         f32x4 (&acc)[4][4]) {
    const int sr = t >> 2, sk = (t & 3) * 8;
    for (int k0 = 0; k0 < K; k0 += 32) {
        #pragma unroll
        for (int p = 0; p < 2; ++p) {
            int r = sr + p * 64;
            *reinterpret_cast<int4*>(&As[r * LDK + sk]) =
                *reinterpret_cast<const int4*>(&Ab[(size_t)(m0 + r) * K + k0 + sk]);
            *reinterpret_cast<int4*>(&Wsm[r * LDK + sk]) =
                *reinterpret_cast<const int4*>(&Wt[(size_t)r * ldW + wcol0 + k0 + sk]);
        }
        __syncthreads();
        short8v af[4], wf[4];
        #pragma unroll
        for (int m = 0; m < 4; ++m)
            af[m] = *reinterpret_cast<const short8v*>(&As[(wr * 64 + m * 16 + fr) * LDK + fq * 8]);
        #pragma unroll
        for (int n = 0; n < 4; ++n)
            wf[n] = *reinterpret_cast<const short8v*>(&Wsm[(wc * 64 + n * 16 + fr) * LDK + fq * 8]);
        #pragma unroll
        for (int m = 0; m < 4; ++m)
            #pragma unroll
            for (int n = 0; n < 4; ++n)
                acc[m][n] = __builtin_amdgcn_mfma_f32_16x16x32_bf16(af[m], wf[n], acc[m][n], 0, 0, 0);
        __syncthreads();
    }
}

// ---------------------------------------------------------------- fused knn (z-window) + x_up interp  ∥  coarse PQ MFMA GEMM
__global__ __launch_bounds__(256) void knn_cpq(const float* __restrict__ pos,
                                               const float4* __restrict__ sposg,
                                               const int* __restrict__ offZ,
                                               const float* __restrict__ xc,
                                               int* __restrict__ idx,
                                               float* __restrict__ wn,
                                               ushort* __restrict__ xup,
                                               const ushort* __restrict__ xb16,
                                               const ushort* __restrict__ W1eT,
                                               ushort* __restrict__ PQc) {
    __shared__ ushort As[128 * LDK];
    __shared__ ushort Wsm[128 * LDK];
    const int bx = blockIdx.x;
    const int tid = threadIdx.x;
    if (bx < B * NC / 128) {
        // ---- coarse PQ GEMM: M=2048, N=128 (P|Q), K=128
        const int b = bx >> 4, m0 = (bx & 15) * 128;
        const int lane = tid & 63, wid = tid >> 6;
        const int wr = wid >> 1, wc = wid & 1;
        const int fr = lane & 15, fq = lane >> 4;
        f32x4 acc[4][4];
        #pragma unroll
        for (int m = 0; m < 4; ++m)
            #pragma unroll
            for (int n = 0; n < 4; ++n) acc[m][n] = (f32x4){0.f, 0.f, 0.f, 0.f};
        mfma_seg(xb16 + (size_t)b * NC * 128, 128, m0, W1eT, 128, 0,
                 As, Wsm, tid, wr, wc, fr, fq, acc);
        ushort* Cb = PQc + (size_t)b * NC * 128;
        #pragma unroll
        for (int m = 0; m < 4; ++m)
            #pragma unroll
            for (int n = 0; n < 4; ++n) {
                int col = wc * 64 + n * 16 + fr;
                #pragma unroll
                for (int r = 0; r < 4; ++r) {
                    int row = m0 + wr * 64 + m * 16 + fq * 4 + r;
                    Cb[(size_t)row * 128 + col] = f2b(acc[m][n][r]);
                }
            }
        return;
    }
    // ---- knn + x_up interpolation
    const int t2 = bx - B * NC / 128;
    const int b = t2 >> 10;
    const int node = (t2 & 1023) * 8 + (tid >> 5);
    const int lane = tid & 31;
    const float* pf = pos + ((size_t)b * NF + node) * 3;
    const float px = pf[0], py = pf[1], pz = pf[2];
    const float4* sp = sposg + (size_t)b * NC;
    const int zb = min(max((int)(pz * (float)ZB), 0), ZB - 1);
    const int zlo = max(zb - 32, 0), zhi = min(zb + 32, ZB - 1);
    const int j0 = offZ[b * (ZB + 1) + zlo];
    const int j1 = offZ[b * (ZB + 1) + zhi + 1];
    float d0 = FLT_MAX, d1 = FLT_MAX, d2 = FLT_MAX;
    int i0 = 0, i1 = 0, i2 = 0;
    for (int j = j0 + lane; j < j1; j += 32) {
        float4 s = sp[j];
        float ddx = __fsub_rn(px, s.x);
        float ddy = __fsub_rn(py, s.y);
        float ddz = __fsub_rn(pz, s.z);
        float d = __fadd_rn(__fadd_rn(__fmul_rn(ddx, ddx), __fmul_rn(ddy, ddy)),
                            __fmul_rn(ddz, ddz));
        ins3(d, __float_as_int(s.w), d0, d1, d2, i0, i1, i2);
    }
    merge32(d0, d1, d2, i0, i1, i2);
    float bd = 1e30f;
    if (zlo > 0)      bd = fminf(bd, pz - (float)zlo * (1.0f / ZB));
    if (zhi < ZB - 1) bd = fminf(bd, (float)(zhi + 1) * (1.0f / ZB) - pz);
    bd *= 0.9999f;
    if (__any(d2 > bd * bd)) {
        d0 = d1 = d2 = FLT_MAX; i0 = i1 = i2 = 0;
        for (int j = lane; j < NC; j += 32) {
            float4 s = sp[j];
            float ddx = __fsub_rn(px, s.x);
            float ddy = __fsub_rn(py, s.y);
            float ddz = __fsub_rn(pz, s.z);
            float d = __fadd_rn(__fadd_rn(__fmul_rn(ddx, ddx), __fmul_rn(ddy, ddy)),
                                __fmul_rn(ddz, ddz));
            ins3(d, __float_as_int(s.w), d0, d1, d2, i0, i1, i2);
        }
        merge32(d0, d1, d2, i0, i1, i2);
    }
    float w0 = 1.0f / (d0 + 1e-16f);
    float w1 = 1.0f / (d1 + 1e-16f);
    float w2 = 1.0f / (d2 + 1e-16f);
    float inv = 1.0f / (w0 + w1 + w2);
    w0 *= inv; w1 *= inv; w2 *= inv;
    if (lane == 0) {
        size_t o = ((size_t)b * NF + node) * 3;
        idx[o] = i0; idx[o + 1] = i1; idx[o + 2] = i2;
        wn[o] = w0; wn[o + 1] = w1; wn[o + 2] = w2;
    }
    const float* xb = xc + (size_t)b * NC * CIN;
    float4 a = *(const float4*)&xb[(size_t)i0 * CIN + lane * 4];
    float4 bb = *(const float4*)&xb[(size_t)i1 * CIN + lane * 4];
    float4 cc = *(const float4*)&xb[(size_t)i2 * CIN + lane * 4];
    ushort4 u;
    u.x = f2b(w0 * a.x + w1 * bb.x + w2 * cc.x);
    u.y = f2b(w0 * a.y + w1 * bb.y + w2 * cc.y);
    u.z = f2b(w0 * a.z + w1 * bb.z + w2 * cc.z);
    u.w = f2b(w0 * a.w + w1 * bb.w + w2 * cc.w);
    *(ushort4*)&xup[((size_t)b * NF + node) * CIN + lane * 4] = u;
}

// ---------------------------------------------------------------- shared fine-PQ body (one A-stage feeds both W k-slices)
__device__ __forceinline__ void pq_body(const ushort* __restrict__ Ab, int K,
                                        const ushort* __restrict__ Wt, int ldW, int m0,
                                        ushort* __restrict__ Pb, ushort* __restrict__ Qb,
                                        int t, ushort* As, ushort* Ws0, ushort* Ws1) {
    const int lane = t & 63, wid = t >> 6;
    const int wr = wid >> 1, wc = wid & 1;
    const int fr = lane & 15, fq = lane >> 4;
    const int sr = t >> 2, sk = (t & 3) * 8;
    f32x4 accP[4][4], accQ[4][4];
    #pragma unroll
    for (int m = 0; m < 4; ++m)
        #pragma unroll
        for (int n = 0; n < 4; ++n) {
            accP[m][n] = (f32x4){0.f, 0.f, 0.f, 0.f};
            accQ[m][n] = (f32x4){0.f, 0.f, 0.f, 0.f};
        }
    for (int k0 = 0; k0 < K; k0 += 32) {
        #pragma unroll
        for (int p = 0; p < 2; ++p) {
            int r = sr + p * 64;
            *reinterpret_cast<int4*>(&As[r * LDK + sk]) =
                *reinterpret_cast<const int4*>(&Ab[(size_t)(m0 + r) * K + k0 + sk]);
            *reinterpret_cast<int4*>(&Ws0[r * LDK + sk]) =
                *reinterpret_cast<const int4*>(&Wt[(size_t)r * ldW + k0 + sk]);
            *reinterpret_cast<int4*>(&Ws1[r * LDK + sk]) =
                *reinterpret_cast<const int4*>(&Wt[(size_t)r * ldW + K + k0 + sk]);
        }
        __syncthreads();
        short8v af[4], w0[4], w1[4];
        #pragma unroll
        for (int m = 0; m < 4; ++m)
            af[m] = *reinterpret_cast<const short8v*>(&As[(wr * 64 + m * 16 + fr) * LDK + fq * 8]);
        #pragma unroll
        for (int n = 0; n < 4; ++n) {
            w0[n] = *reinterpret_cast<const short8v*>(&Ws0[(wc * 64 + n * 16 + fr) * LDK + fq * 8]);
            w1[n] = *reinterpret_cast<const short8v*>(&Ws1[(wc * 64 + n * 16 + fr) * LDK + fq * 8]);
        }
        #pragma unroll
        for (int m = 0; m < 4; ++m)
            #pragma unroll
            for (int n = 0; n < 4; ++n) {
                accP[m][n] = __builtin_amdgcn_mfma_f32_16x16x32_bf16(af[m], w0[n], accP[m][n], 0, 0, 0);
                accQ[m][n] = __builtin_amdgcn_mfma_f32_16x16x32_bf16(af[m], w1[n], accQ[m][n], 0, 0, 0);
            }
        __syncthreads();
    }
    #pragma unroll
    for (int m = 0; m < 4; ++m)
        #pragma unroll
        for (int n = 0; n < 4; ++n) {
            int col = wc * 64 + n * 16 + fr;
            #pragma unroll
            for (int r = 0; r < 4; ++r) {
                int row = m0 + wr * 64 + m * 16 + fq * 4 + r;
                Pb[(size_t)row * 128 + col] = f2b(accP[m][n][r]);
                Qb[(size_t)row * 128 + col] = f2b(accQ[m][n][r]);
            }
        }
}

// ---------------------------------------------------------------- fine agg inner body (bf16 io, C=128)
__device__ __forceinline__ void agg_fine(const ushort* __restrict__ Pb, const ushort* __restrict__ Qb,
                                         const float* __restrict__ bias, int start, int cnt,
                                         const int* __restrict__ sl, ushort* __restrict__ aggRow,
                                         int dst, int lane) {
    const int c0 = lane, c1 = lane + 64;
    const float q0 = b2f(Qb[(size_t)dst * 128 + c0]) + bias[c0];
    const float q1 = b2f(Qb[(size_t)dst * 128 + c1]) + bias[c1];
    float a0 = 0.0f, a1 = 0.0f;
    int i = 0;
    for (; i + 4 <= cnt; i += 4) {
        int s0 = sl[i], s1 = sl[i + 1], s2 = sl[i + 2], s3 = sl[i + 3];
        ushort p00 = Pb[(size_t)s0 * 128 + c0], p01 = Pb[(size_t)s0 * 128 + c1];
        ushort p10 = Pb[(size_t)s1 * 128 + c0], p11 = Pb[(size_t)s1 * 128 + c1];
        ushort p20 = Pb[(size_t)s2 * 128 + c0], p21 = Pb[(size_t)s2 * 128 + c1];
        ushort p30 = Pb[(size_t)s3 * 128 + c0], p31 = Pb[(size_t)s3 * 128 + c1];
        float m;
        m = b2f(p00) + q0; m = m > 0.0f ? m : 0.01f * m; a0 += m;
        m = b2f(p01) + q1; m = m > 0.0f ? m : 0.01f * m; a1 += m;
        m = b2f(p10) + q0; m = m > 0.0f ? m : 0.01f * m; a0 += m;
        m = b2f(p11) + q1; m = m > 0.0f ? m : 0.01f * m; a1 += m;
        m = b2f(p20) + q0; m = m > 0.0f ? m : 0.01f * m; a0 += m;
        m = b2f(p21) + q1; m = m > 0.0f ? m : 0.01f * m; a1 += m;
        m = b2f(p30) + q0; m = m > 0.0f ? m : 0.01f * m; a0 += m;
        m = b2f(p31) + q1; m = m > 0.0f ? m : 0.01f * m; a1 += m;
    }
    for (; i < cnt; ++i) {
        int src = sl[i];
        float m0 = b2f(Pb[(size_t)src * 128 + c0]) + q0; m0 = m0 > 0.0f ? m0 : 0.01f * m0;
        float m1 = b2f(Pb[(size_t)src * 128 + c1]) + q1; m1 = m1 > 0.0f ? m1 : 0.01f * m1;
        a0 += m0; a1 += m1;
    }
    __builtin_nontemporal_store(f2b(a0), &aggRow[(size_t)dst * 128 + c0]);
    __builtin_nontemporal_store(f2b(a1), &aggRow[(size_t)dst * 128 + c1]);
}

// ---------------------------------------------------------------- L6: skip-branch PQ GEMM  ∥  coarse agg (bf16)
__global__ __launch_bounds__(256) void pqs_aggc(const ushort* __restrict__ xupb,
                                                const ushort* __restrict__ WseT,
                                                ushort* __restrict__ PS, ushort* __restrict__ QS,
                                                const ushort* __restrict__ PQc,
                                                const float* __restrict__ b1e,
                                                const int* __restrict__ offC,
                                                const int* __restrict__ cntC,
                                                const int* __restrict__ csrC,
                                                ushort* __restrict__ aggC) {
    __shared__ ushort As[128 * LDK];
    __shared__ ushort Ws0[128 * LDK];
    __shared__ ushort Ws1[128 * LDK];
    const int bx = blockIdx.x;
    const int tid = threadIdx.x;
    if (bx < B * NF / 128) {
        const int b = bx >> 6, m0 = (bx & 63) * 128;
        pq_body(xupb + (size_t)b * NF * 128, 128, WseT, 256, m0,
                PS + (size_t)b * NF * 128, QS + (size_t)b * NF * 128, tid, As, Ws0, Ws1);
        return;
    }
    // coarse agg: C=64, P = PQc cols 0-63, Q = cols 64-127
    const int t2 = bx - B * NF / 128;
    const int b = t2 >> 9;
    const int dst = (t2 & 511) * 4 + (tid >> 6);
    const int lane = tid & 63;
    const ushort* Pb = PQc + (size_t)b * NC * 128;
    const int start = offC[b * NC + dst];
    const int cnt = cntC[b * NC + dst];
    const int* sl = csrC + (size_t)b * EC + start;
    const float q = b2f(Pb[(size_t)dst * 128 + 64 + lane]) + b1e[lane];
    float a = 0.0f;
    for (int i = 0; i < cnt; ++i) {
        int src = sl[i];
        float m = b2f(Pb[(size_t)src * 128 + lane]) + q; m = m > 0.0f ? m : 0.01f * m;
        a += m;
    }
    aggC[(size_t)b * NC * 64 + (size_t)dst * 64 + lane] = f2b(a);
}

// ---------------------------------------------------------------- L7: coarse x1 node GEMM (256-row tile, N=64)  ∥  skip agg
__global__ __launch_bounds__(256) void x1_aggs(const ushort* __restrict__ xb16,
                                               const ushort* __restrict__ aggC,
                                               const ushort* __restrict__ W1nT,
                                               const float* __restrict__ b1n,
                                               ushort* __restrict__ x1b,
                                               const ushort* __restrict__ PS,
                                               const ushort* __restrict__ QS,
                                               const float* __restrict__ bse,
                                               const int* __restrict__ offF,
                                               const int* __restrict__ cntF,
                                               const int* __restrict__ csrF,
                                               ushort* __restrict__ aggS) {
    __shared__ ushort As[256 * LDK];
    __shared__ ushort Wsm[64 * LDK];
    const int bx = blockIdx.x;
    const int tid = threadIdx.x;
    if (bx < B * NC / 256) {
        // x1 = lrelu([xb16 | aggC] @ W1nT + b1n), 256 rows x 64 cols, 4 waves vertical
        const int b = bx >> 3, m0 = (bx & 7) * 256;
        const int lane = tid & 63, wr = tid >> 6;
        const int fr = lane & 15, fq = lane >> 4;
        const int sr = tid >> 2, sk = (tid & 3) * 8;
        f32x4 acc[4][4];
        #pragma unroll
        for (int m = 0; m < 4; ++m)
            #pragma unroll
            for (int n = 0; n < 4; ++n) acc[m][n] = (f32x4){0.f, 0.f, 0.f, 0.f};
        // segment 1: A = xb16, K=128, W cols 0-127
        const ushort* A1 = xb16 + (size_t)b * NC * 128;
        for (int k0 = 0; k0 < 128; k0 += 32) {
            #pragma unroll
            for (int p = 0; p < 4; ++p) {
                int r = sr + p * 64;
                *reinterpret_cast<int4*>(&As[r * LDK + sk]) =
                    *reinterpret_cast<const int4*>(&A1[(size_t)(m0 + r) * 128 + k0 + sk]);
            }
            *reinterpret_cast<int4*>(&Wsm[sr * LDK + sk]) =
                *reinterpret_cast<const int4*>(&W1nT[(size_t)sr * 192 + k0 + sk]);
            __syncthreads();
            short8v af[4], wf[4];
            #pragma unroll
            for (int m = 0; m < 4; ++m)
                af[m] = *reinterpret_cast<const short8v*>(&As[(wr * 64 + m * 16 + fr) * LDK + fq * 8]);
            #pragma unroll
            for (int n = 0; n < 4; ++n)
                wf[n] = *reinterpret_cast<const short8v*>(&Wsm[(n * 16 + fr) * LDK + fq * 8]);
            #pragma unroll
            for (int m = 0; m < 4; ++m)
                #pragma unroll
                for (int n = 0; n < 4; ++n)
                    acc[m][n] = __builtin_amdgcn_mfma_f32_16x16x32_bf16(af[m], wf[n], acc[m][n], 0, 0, 0);
            __syncthreads();
        }
        // segment 2: A = aggC, K=64, W cols 128-191
        const ushort* A2 = aggC + (size_t)b * NC * 64;
        for (int k0 = 0; k0 < 64; k0 += 32) {
            #pragma unroll
            for (int p = 0; p < 4; ++p) {
                int r = sr + p * 64;
                *reinterpret_cast<int4*>(&As[r * LDK + sk]) =
                    *reinterpret_cast<const int4*>(&A2[(size_t)(m0 + r) * 64 + k0 + sk]);
            }
            *reinterpret_cast<int4*>(&Wsm[sr * LDK + sk]) =
                *reinterpret_cast<const int4*>(&W1nT[(size_t)sr * 192 + 128 + k0 + sk]);
            __syncthreads();
            short8v af[4], wf[4];
            #pragma unroll
            for (int m = 0; m < 4; ++m)
                af[m] = *reinterpret_cast<const short8v*>(&As[(wr * 64 + m * 16 + fr) * LDK + fq * 8]);
            #pragma unroll
            for (int n = 0; n < 4; ++n)
                wf[n] = *reinterpret_cast<const short8v*>(&Wsm[(n * 16 + fr) * LDK + fq * 8]);
            #pragma unroll
            for (int m = 0; m < 4; ++m)
                #pragma unroll
                for (int n = 0; n < 4; ++n)
                    acc[m][n] = __builtin_amdgcn_mfma_f32_16x16x32_bf16(af[m], wf[n], acc[m][n], 0, 0, 0);
            __syncthreads();
        }
        ushort* Cb = x1b + (size_t)b * NC * 64;
        #pragma unroll
        for (int m = 0; m < 4; ++m)
            #pragma unroll
            for (int n = 0; n < 4; ++n) {
                int col = n * 16 + fr;
                float bv = b1n[col];
                #pragma unroll
                for (int r = 0; r < 4; ++r) {
                    int row = m0 + wr * 64 + m * 16 + fq * 4 + r;
                    float v = acc[m][n][r] + bv;
                    v = v > 0.0f ? v : 0.01f * v;
                    Cb[(size_t)row * 64 + col] = f2b(v);
                }
            }
        return;
    }
    // skip agg (XCD-spread: graph = t&3)
    const int t2 = bx - B * NC / 256;
    const int b = t2 & 3;
    const int dst = (t2 >> 2) * 4 + (tid >> 6);
    const int lane = tid & 63;
    const int start = offF[b * NF + dst];
    const int cnt = cntF[b * NF + dst];
    agg_fine(PS + (size_t)b * NF * 128, QS + (size_t)b * NF * 128, bse, start, cnt,
             csrF + (size_t)b * EF + start, aggS + (size_t)b * NF * 128, dst, lane);
}

// ---------------------------------------------------------------- x1_up interp (bf16 source, C=64: 16 lanes/node)
__global__ __launch_bounds__(256) void interp_x1(const ushort* __restrict__ x1b,
                                                 const int* __restrict__ idx,
                                                 const float* __restrict__ wn,
                                                 ushort* __restrict__ out) {
    const int b = blockIdx.y;
    const int node = blockIdx.x * 16 + (threadIdx.x >> 4);
    const int lane = threadIdx.x & 15;
    size_t o = ((size_t)b * NF + node) * 3;
    int i0 = idx[o], i1 = idx[o + 1], i2 = idx[o + 2];
    float w0 = wn[o], w1 = wn[o + 1], w2 = wn[o + 2];
    const ushort* xb = x1b + (size_t)b * NC * 64;
    ushort4 a = *(const ushort4*)&xb[(size_t)i0 * 64 + lane * 4];
    ushort4 bb = *(const ushort4*)&xb[(size_t)i1 * 64 + lane * 4];
    ushort4 cc = *(const ushort4*)&xb[(size_t)i2 * 64 + lane * 4];
    ushort4 u;
    u.x = f2b(w0 * b2f(a.x) + w1 * b2f(bb.x) + w2 * b2f(cc.x));
    u.y = f2b(w0 * b2f(a.y) + w1 * b2f(bb.y) + w2 * b2f(cc.y));
    u.z = f2b(w0 * b2f(a.z) + w1 * b2f(bb.z) + w2 * b2f(cc.z));
    u.w = f2b(w0 * b2f(a.w) + w1 * b2f(bb.w) + w2 * b2f(cc.w));
    *(ushort4*)&out[((size_t)b * NF + node) * 64 + lane * 4] = u;
}

// ---------------------------------------------------------------- main-branch PQ GEMM (K=64)
__global__ __launch_bounds__(256) void pq2_kernel(const ushort* __restrict__ x1upb,
                                                  const ushort* __restrict__ W2eT,
                                                  ushort* __restrict__ P2, ushort* __restrict__ Q2) {
    __shared__ ushort As[128 * LDK];
    __shared__ ushort Ws0[128 * LDK];
    __shared__ ushort Ws1[128 * LDK];
    const int bx = blockIdx.x;
    const int b = bx >> 6, m0 = (bx & 63) * 128;
    pq_body(x1upb + (size_t)b * NF * 64, 64, W2eT, 128, m0,
            P2 + (size_t)b * NF * 128, Q2 + (size_t)b * NF * 128, threadIdx.x, As, Ws0, Ws1);
}

// ---------------------------------------------------------------- main-branch agg (XCD-spread)
__global__ __launch_bounds__(256) void agg2_kernel(const ushort* __restrict__ P2,
                                                   const ushort* __restrict__ Q2,
                                                   const float* __restrict__ b2e,
                                                   const int* __restrict__ offF,
                                                   const int* __restrict__ cntF,
                                                   const int* __restrict__ csrF,
                                                   ushort* __restrict__ agg2) {
    const int bx = blockIdx.x;
    const int b = bx & 3;
    const int dst = (bx >> 2) * 4 + (threadIdx.x >> 6);
    const int lane = threadIdx.x & 63;
    const int start = offF[b * NF + dst];
    const int cnt = cntF[b * NF + dst];
    agg_fine(P2 + (size_t)b * NF * 128, Q2 + (size_t)b * NF * 128, b2e, start, cnt,
             csrF + (size_t)b * EF + start, agg2 + (size_t)b * NF * 128, dst, lane);
}

// ---------------------------------------------------------------- fused dual-branch node GEMM + BN stats
__global__ __launch_bounds__(256) void mfma_node2(
    const ushort* __restrict__ A1, const ushort* __restrict__ A2,
    const ushort* __restrict__ Wt1, const float* __restrict__ bias1,
    const ushort* __restrict__ A3, const ushort* __restrict__ A4,
    const ushort* __restrict__ Wt2, const float* __restrict__ bias2,
    float* __restrict__ y, float* __restrict__ stats) {
    __shared__ ushort As[128 * LDK];
    __shared__ ushort Wsm[128 * LDK];
    const int t = threadIdx.x;
    const int lane = t & 63, wid = t >> 6;
    const int wr = wid >> 1, wc = wid & 1;
    const int fr = lane & 15, fq = lane >> 4;
    const int b = blockIdx.z;
    const int m0 = blockIdx.x * 128;
    f32x4 acc1[4][4], acc2[4][4];
    #pragma unroll
    for (int m = 0; m < 4; ++m)
        #pragma unroll
        for (int n = 0; n < 4; ++n) {
            acc1[m][n] = (f32x4){0.f, 0.f, 0.f, 0.f};
            acc2[m][n] = (f32x4){0.f, 0.f, 0.f, 0.f};
        }
    mfma_seg(A1 + (size_t)b * NF * 64,  64,  m0, Wt1, 192, 0,   As, Wsm, t, wr, wc, fr, fq, acc1);
    mfma_seg(A2 + (size_t)b * NF * 128, 128, m0, Wt1, 192, 64,  As, Wsm, t, wr, wc, fr, fq, acc1);
    mfma_seg(A3 + (size_t)b * NF * 128, 128, m0, Wt2, 256, 0,   As, Wsm, t, wr, wc, fr, fq, acc2);
    mfma_seg(A4 + (size_t)b * NF * 128, 128, m0, Wt2, 256, 128, As, Wsm, t, wr, wc, fr, fq, acc2);
    float* Yb = y + (size_t)b * NF * 128;
    float lsum[4] = {0.f, 0.f, 0.f, 0.f}, lsq[4] = {0.f, 0.f, 0.f, 0.f};
    #pragma unroll
    for (int m = 0; m < 4; ++m)
        #pragma unroll
        for (int n = 0; n < 4; ++n) {
            int col = wc * 64 + n * 16 + fr;
            float bv1 = bias1[col], bv2 = bias2[col];
            #pragma unroll
            for (int r = 0; r < 4; ++r) {
                int row = m0 + wr * 64 + m * 16 + fq * 4 + r;
                float v1 = acc1[m][n][r] + bv1; v1 = v1 > 0.0f ? v1 : 0.01f * v1;
                float v2 = acc2[m][n][r] + bv2; v2 = v2 > 0.0f ? v2 : 0.01f * v2;
                float v = v1 + v2;
                Yb[(size_t)row * 128 + col] = v;
                lsum[n] += v;
                lsq[n] = fmaf(v, v, lsq[n]);
            }
        }
    __syncthreads();
    float* ssum = reinterpret_cast<float*>(As);
    float* ssq  = ssum + 128;
    if (t < 128) { ssum[t] = 0.0f; ssq[t] = 0.0f; }
    __syncthreads();
    #pragma unroll
    for (int n = 0; n < 4; ++n) {
        int col = wc * 64 + n * 16 + fr;
        atomicAdd(&ssum[col], lsum[n]);
        atomicAdd(&ssq[col], lsq[n]);
    }
    __syncthreads();
    if (t < 128) {
        atomicAdd(&stats[t], ssum[t]);
        atomicAdd(&stats[128 + t], ssq[t]);
    }
}

// ---------------------------------------------------------------- batch-norm finalize + wf via inv map
__global__ __launch_bounds__(256) void bn_final(float* __restrict__ xs,
                                                const float* __restrict__ stats,
                                                const float* __restrict__ gamma,
                                                const float* __restrict__ beta,
                                                float* __restrict__ wf,
                                                const float* __restrict__ wts,
                                                const int* __restrict__ inv) {
    const long i = (long)blockIdx.x * 256 + threadIdx.x;   // float4 index
    const long g4 = i * 4;
    const int c = (int)(g4 & (COUT - 1));
    const float invN = 1.0f / (float)(B * NF);
    float4 v = *(float4*)&xs[g4];
    float vv[4] = {v.x, v.y, v.z, v.w};
    #pragma unroll
    for (int k = 0; k < 4; ++k) {
        int ck = c + k;
        float mu = stats[ck] * invN;
        float var = stats[COUT + ck] * invN - mu * mu;
        float t = (vv[k] - mu) * rsqrtf(var + 1e-5f) * gamma[ck] + beta[ck];
        vv[k] = t > 0.0f ? t : 0.01f * t;
    }
    *(float4*)&xs[g4] = make_float4(vv[0], vv[1], vv[2], vv[3]);
    if (i < (long)B * NF) {
        int iv = inv[i];
        wf[i] = (iv >= 0) ? wts[iv] : 0.0f;
    }
}

extern "C" void kernel_launch(void* const* d_in, const int* in_sizes, int n_in,
                              void* d_out, int out_size, void* d_ws, size_t ws_size,
                              hipStream_t stream) {
    const float* x    = (const float*)d_in[0];
    const float* wts  = (const float*)d_in[1];
    const float* pos  = (const float*)d_in[2];
    const float* W1e  = (const float*)d_in[3];
    const float* b1e  = (const float*)d_in[4];
    const float* W1n  = (const float*)d_in[5];
    const float* b1n  = (const float*)d_in[6];
    const float* W2e  = (const float*)d_in[7];
    const float* b2e  = (const float*)d_in[8];
    const float* W2n  = (const float*)d_in[9];
    const float* b2n  = (const float*)d_in[10];
    const float* Wse  = (const float*)d_in[11];
    const float* bse  = (const float*)d_in[12];
    const float* Wsn  = (const float*)d_in[13];
    const float* bsn  = (const float*)d_in[14];
    const float* gamma= (const float*)d_in[15];
    const float* beta = (const float*)d_in[16];
    const int*   mask = (const int*)d_in[17];
    const int*   ec   = (const int*)d_in[18];
    const int*   ef   = (const int*)d_in[19];

    float* ws = (float*)d_ws;
    // ---- f32 region
    int*    idxb  = (int*)ws;                              // B*NF*3
    float*  wnb   = ws + 98304;                            // B*NF*3
    float4* sposg = (float4*)(ws + 196608);                // B*NC float4 (z-sorted)
    float*  stats = ws + 196608 + 32768;                   // 256 (contiguous with counts)
    // ---- int region (stats+counts contiguous for single memset)
    int* cntC  = (int*)(stats + 256);                      // B*NC
    int* cntF  = cntC + B * NC;                            // B*NF
    int* cntZ  = cntF + B * NF;                            // B*ZB
    int* offC  = cntZ + B * ZB;                            // B*NC
    int* curC  = offC + B * NC;
    int* offF  = curC + B * NC;                            // B*NF
    int* curF  = offF + B * NF;
    int* offZ  = curF + B * NF;                            // B*(ZB+1)
    int* curZ  = offZ + B * (ZB + 1);
    int* csrC  = curZ + B * (ZB + 1);                      // B*EC
    int* csrF  = csrC + B * EC;                            // B*EF
    int* invm  = csrF + B * EF;                            // B*NF
    // ---- bf16 region
    size_t foff = (size_t)(invm + (size_t)B * NF - (int*)ws);
    foff = (foff + 7) & ~(size_t)7;
    ushort* xupb  = (ushort*)(ws + foff);                  // B*NF*128
    ushort* x1upb = xupb  + (size_t)B * NF * 128;          // B*NF*64
    ushort* P2b   = x1upb + (size_t)B * NF * 64;           // B*NF*128
    ushort* Q2b   = P2b   + (size_t)B * NF * 128;          // B*NF*128
    ushort* PSb   = Q2b   + (size_t)B * NF * 128;          // B*NF*128
    ushort* QSb   = PSb   + (size_t)B * NF * 128;          // B*NF*128
    ushort* agg2b = QSb   + (size_t)B * NF * 128;          // B*NF*128
    ushort* aggSb = agg2b + (size_t)B * NF * 128;          // B*NF*128
    ushort* xb16  = aggSb + (size_t)B * NF * 128;          // B*NC*128
    ushort* PQc   = xb16  + (size_t)B * NC * 128;          // B*NC*128
    ushort* aggCb = PQc   + (size_t)B * NC * 128;          // B*NC*64
    ushort* x1b   = aggCb + (size_t)B * NC * 64;           // B*NC*64
    ushort* W2eT  = x1b   + (size_t)B * NC * 64;           // 128*128
    ushort* W2nT  = W2eT  + 128 * 128;                     // 128*192
    ushort* WseT  = W2nT  + 128 * 192;                     // 128*256
    ushort* WsnT  = WseT  + 128 * 256;                     // 128*256
    ushort* W1eT  = WsnT  + 128 * 256;                     // 128*128
    ushort* W1nT  = W1eT  + 128 * 128;                     // 64*192

    float* y  = (float*)d_out;                             // B*NF*128
    float* wf = y + (size_t)B * NF * COUT;                 // B*NF

    // ---- prep
    hipMemsetAsync(stats, 0, 256 * 4 + (size_t)B * (NC + NF + ZB) * 4, stream);
    count_all<<<dim3(EF / 256, B, 6), 256, 0, stream>>>(
        ec, ef, mask, pos, cntC, cntF, cntZ, invm,
        W2e, W2n, Wse, Wsn, W2eT, W2nT, WseT, WsnT,
        W1e, W1n, W1eT, W1nT, x, xb16);
    scan_all<<<dim3(3 * B), 1024, 0, stream>>>(cntC, offC, curC, cntF, offF, curF, cntZ, offZ, curZ);
    fill_all<<<dim3(EF / 256, B, 3), 256, 0, stream>>>(ec, ef, mask, pos, curC, curF, curZ,
                                                       csrC, csrF, sposg, invm);

    // ---- L5: coarse PQ GEMM ∥ knn + x_up interp
    knn_cpq<<<dim3(B * NC / 128 + B * NF / 8), 256, 0, stream>>>(
        pos, sposg, offZ, x, idxb, wnb, xupb, xb16, W1eT, PQc);

    // ---- L6: skip-branch PQ GEMM ∥ coarse agg
    pqs_aggc<<<dim3(B * NF / 128 + B * NC / 4), 256, 0, stream>>>(
        xupb, WseT, PSb, QSb, PQc, b1e, offC, cntC, csrC, aggCb);

    // ---- L7: coarse x1 node GEMM ∥ skip agg
    x1_aggs<<<dim3(B * NC / 256 + B * NF / 4), 256, 0, stream>>>(
        xb16, aggCb, W1nT, b1n, x1b, PSb, QSb, bse, offF, cntF, csrF, aggSb);

    // ---- L8: x1_up interp (bf16)
    interp_x1<<<dim3(NF / 16, B), 256, 0, stream>>>(x1b, idxb, wnb, x1upb);

    // ---- L9/L10: main-branch PQ GEMM, agg
    pq2_kernel<<<dim3(B * NF / 128), 256, 0, stream>>>(x1upb, W2eT, P2b, Q2b);
    agg2_kernel<<<dim3(B * NF / 4), 256, 0, stream>>>(P2b, Q2b, b2e, offF, cntF, csrF, agg2b);

    // ---- L11: fused dual-branch node GEMM + BN stats -> y
    mfma_node2<<<dim3(NF / 128, 1, B), 256, 0, stream>>>(
        x1upb, agg2b, W2nT, b2n, xupb, aggSb, WsnT, bsn, y, stats);

    // ---- L12: batch norm finalize + lrelu + direct w_fine write
    bn_final<<<dim3((long)B * NF * COUT / 1024), 256, 0, stream>>>(y, stats, gamma, beta, wf, wts, invm);
}

// Round 13
// 190.502 us; speedup vs baseline: 1.2599x; 1.2599x over previous
//
#include <hip/hip_runtime.h>
#include <hip/hip_bf16.h>
#include <cfloat>

#define B 4
#define NC 2048
#define NF 8192
#define CIN 128
#define CH 64
#define COUT 128
#define EC 16384
#define EF 65536
#define ZB 256          // z-sort bins
#define LDK 40

typedef __attribute__((ext_vector_type(8))) short short8v;
typedef __attribute__((ext_vector_type(4))) float f32x4;

__device__ __forceinline__ ushort f2b(float v) {
    __hip_bfloat16 h = __float2bfloat16(v);
    return *reinterpret_cast<ushort*>(&h);
}
__device__ __forceinline__ float b2f(ushort u) {
    __hip_bfloat16 h = *reinterpret_cast<__hip_bfloat16*>(&u);
    return __bfloat162float(h);
}

// ---------------------------------------------------------------- combined prep: hists / z-bins / weight transposes / conversions
__global__ void count_all(const int* __restrict__ ec, const int* __restrict__ ef,
                          const int* __restrict__ mask, const float* __restrict__ pos,
                          int* __restrict__ cntC, int* __restrict__ cntF, int* __restrict__ cntZ,
                          int* __restrict__ inv,
                          const float* __restrict__ W2e, const float* __restrict__ W2n,
                          const float* __restrict__ Wse, const float* __restrict__ Wsn,
                          ushort* __restrict__ W2eT, ushort* __restrict__ W2nT,
                          ushort* __restrict__ WseT, ushort* __restrict__ WsnT,
                          const float* __restrict__ W1e, const float* __restrict__ W1n,
                          ushort* __restrict__ W1eT, ushort* __restrict__ W1nT,
                          const float* __restrict__ x, ushort* __restrict__ xb16) {
    const int b = blockIdx.y, z = blockIdx.z;
    const int i = blockIdx.x * 256 + threadIdx.x;
    if (z == 0) {
        if (i < EC) atomicAdd(&cntC[b * NC + ec[(size_t)b * 2 * EC + EC + i]], 1);
    } else if (z == 1) {
        if (i < EF) atomicAdd(&cntF[b * NF + ef[(size_t)b * 2 * EF + EF + i]], 1);
        if (i < NF) inv[(size_t)b * NF + i] = -1;
    } else if (z == 2) {
        if (i < NC) {
            int m = mask[b * NC + i];
            float pz = pos[((size_t)b * NF + m) * 3 + 2];
            int zb = min(max((int)(pz * (float)ZB), 0), ZB - 1);
            atomicAdd(&cntZ[b * ZB + zb], 1);
        }
    } else if (z == 3) {   // fine weight transposes, b selects matrix
        const float* src; ushort* dst; int K2;
        switch (b) {
            case 0: src = W2e; dst = W2eT; K2 = 128; break;
            case 1: src = W2n; dst = W2nT; K2 = 192; break;
            case 2: src = Wse; dst = WseT; K2 = 256; break;
            default: src = Wsn; dst = WsnT; K2 = 256; break;
        }
        if (i < K2 * 128) {
            int n = i & 127, k = i >> 7;
            dst[(size_t)n * K2 + k] = f2b(src[i]);
        }
    } else if (z == 4) {   // coarse weight transposes
        if (b == 0) {
            if (i < 128 * 128) {   // W1eT[n][k]: n<64 -> P (W1e rows 0-127), n>=64 -> Q (rows 128-255)
                int n = i >> 7, k = i & 127;
                W1eT[i] = f2b(W1e[(size_t)(k + ((n >> 6) << 7)) * 64 + (n & 63)]);
            }
        } else if (b == 1) {
            if (i < 64 * 192) {    // W1nT[n][k] = W1n[k][n]
                int n = i / 192, k = i - n * 192;
                W1nT[i] = f2b(W1n[(size_t)k * 64 + n]);
            }
        }
    } else {               // z == 5: x -> bf16 (per graph b)
        for (int j = i; j < NC * CIN; j += (EF / 256) * 256)
            xb16[(size_t)b * NC * CIN + j] = f2b(x[(size_t)b * NC * CIN + j]);
    }
}

// ---------------------------------------------------------------- combined exclusive scan (grid = 3*B blocks)
template<int N, int OSTR, bool EXTRA>
__device__ __forceinline__ void scan_body(const int* __restrict__ cnt, int* __restrict__ offs,
                                          int* __restrict__ cur, int b, int* part) {
    const int tid = threadIdx.x;
    constexpr int PER = (N + 1023) / 1024;
    int local[PER];
    int s = 0;
    #pragma unroll
    for (int i = 0; i < PER; ++i) {
        int id = tid * PER + i;
        local[i] = s;
        if (id < N) s += cnt[b * N + id];
    }
    part[tid] = s;
    __syncthreads();
    for (int off = 1; off < 1024; off <<= 1) {
        int v = (tid >= off) ? part[tid - off] : 0;
        __syncthreads();
        part[tid] += v;
        __syncthreads();
    }
    int pre = tid ? part[tid - 1] : 0;
    #pragma unroll
    for (int i = 0; i < PER; ++i) {
        int id = tid * PER + i;
        if (id < N) {
            int o = pre + local[i];
            offs[b * OSTR + id] = o;
            cur[b * OSTR + id] = o;
        }
    }
    if (EXTRA && tid == 1023) offs[b * OSTR + N] = part[1023];
}

__global__ __launch_bounds__(1024) void scan_all(
    const int* __restrict__ cntC, int* __restrict__ offC, int* __restrict__ curC,
    const int* __restrict__ cntF, int* __restrict__ offF, int* __restrict__ curF,
    const int* __restrict__ cntZ, int* __restrict__ offZ, int* __restrict__ curZ) {
    __shared__ int part[1024];
    const int cfg = blockIdx.x >> 2;   // B == 4
    const int b = blockIdx.x & 3;
    if (cfg == 0)      scan_body<NC, NC, false>(cntC, offC, curC, b, part);
    else if (cfg == 1) scan_body<NF, NF, false>(cntF, offF, curF, b, part);
    else               scan_body<ZB, ZB + 1, true>(cntZ, offZ, curZ, b, part);
}

// ---------------------------------------------------------------- combined fill: CSRs / z-sorted coarse positions + inv map
__global__ void fill_all(const int* __restrict__ ec, const int* __restrict__ ef,
                         const int* __restrict__ mask, const float* __restrict__ pos,
                         int* __restrict__ curC, int* __restrict__ curF, int* __restrict__ curZ,
                         int* __restrict__ csrC, int* __restrict__ csrF,
                         float4* __restrict__ sposg, int* __restrict__ inv) {
    const int b = blockIdx.y, z = blockIdx.z;
    const int i = blockIdx.x * 256 + threadIdx.x;
    if (z == 0) {
        if (i < EC) {
            const int* eb = ec + (size_t)b * 2 * EC;
            int src = eb[i], dst = eb[EC + i];
            int p = atomicAdd(&curC[b * NC + dst], 1);
            csrC[(size_t)b * EC + p] = src;
        }
    } else if (z == 1) {
        if (i < EF) {
            const int* eb = ef + (size_t)b * 2 * EF;
            int src = eb[i], dst = eb[EF + i];
            int p = atomicAdd(&curF[b * NF + dst], 1);
            csrF[(size_t)b * EF + p] = src;
        }
    } else {
        if (i < NC) {
            int m = mask[b * NC + i];
            const float* p = pos + ((size_t)b * NF + m) * 3;
            float px = p[0], py = p[1], pz = p[2];
            int zb = min(max((int)(pz * (float)ZB), 0), ZB - 1);
            int slot = atomicAdd(&curZ[b * (ZB + 1) + zb], 1);
            sposg[(size_t)b * NC + slot] = make_float4(px, py, pz, __int_as_float(i));
            inv[(size_t)b * NF + m] = b * NC + i;
        }
    }
}

// ---------------------------------------------------------------- top-3 helpers
__device__ __forceinline__ void ins3(float d, int c, float& d0, float& d1, float& d2,
                                     int& i0, int& i1, int& i2) {
    bool lt0 = d < d0, lt1 = d < d1, lt2 = d < d2;
    d2 = lt1 ? d1 : (lt2 ? d : d2);  i2 = lt1 ? i1 : (lt2 ? c : i2);
    d1 = lt0 ? d0 : (lt1 ? d : d1);  i1 = lt0 ? i0 : (lt1 ? c : i1);
    d0 = lt0 ? d  : d0;              i0 = lt0 ? c  : i0;
}
__device__ __forceinline__ void merge32(float& d0, float& d1, float& d2,
                                        int& i0, int& i1, int& i2) {
    #pragma unroll
    for (int off = 1; off <= 16; off <<= 1) {
        float od[3]; int oi[3];
        od[0] = __shfl_xor(d0, off); oi[0] = __shfl_xor(i0, off);
        od[1] = __shfl_xor(d1, off); oi[1] = __shfl_xor(i1, off);
        od[2] = __shfl_xor(d2, off); oi[2] = __shfl_xor(i2, off);
        #pragma unroll
        for (int j = 0; j < 3; ++j) ins3(od[j], oi[j], d0, d1, d2, i0, i1, i2);
    }
}

// ---------------------------------------------------------------- fused knn (z-window) + x_up interpolation (C=128)
__global__ __launch_bounds__(256) void knn_interp(const float* __restrict__ pos,
                                                  const float4* __restrict__ sposg,
                                                  const int* __restrict__ offZ,
                                                  const float* __restrict__ xc,
                                                  int* __restrict__ idx,
                                                  float* __restrict__ wn,
                                                  ushort* __restrict__ xup) {
    const int b = blockIdx.y;
    const int tid = threadIdx.x;
    const int node = blockIdx.x * 8 + (tid >> 5);
    const int lane = tid & 31;
    const float* pf = pos + ((size_t)b * NF + node) * 3;
    const float px = pf[0], py = pf[1], pz = pf[2];
    const float4* sp = sposg + (size_t)b * NC;
    const int zb = min(max((int)(pz * (float)ZB), 0), ZB - 1);
    const int zlo = max(zb - 32, 0), zhi = min(zb + 32, ZB - 1);
    const int j0 = offZ[b * (ZB + 1) + zlo];
    const int j1 = offZ[b * (ZB + 1) + zhi + 1];
    float d0 = FLT_MAX, d1 = FLT_MAX, d2 = FLT_MAX;
    int i0 = 0, i1 = 0, i2 = 0;
    for (int j = j0 + lane; j < j1; j += 32) {
        float4 s = sp[j];
        // match numpy: diff, square, sequential sum — no FMA contraction
        float ddx = __fsub_rn(px, s.x);
        float ddy = __fsub_rn(py, s.y);
        float ddz = __fsub_rn(pz, s.z);
        float d = __fadd_rn(__fadd_rn(__fmul_rn(ddx, ddx), __fmul_rn(ddy, ddy)),
                            __fmul_rn(ddz, ddz));
        ins3(d, __float_as_int(s.w), d0, d1, d2, i0, i1, i2);
    }
    merge32(d0, d1, d2, i0, i1, i2);
    float bd = 1e30f;
    if (zlo > 0)      bd = fminf(bd, pz - (float)zlo * (1.0f / ZB));
    if (zhi < ZB - 1) bd = fminf(bd, (float)(zhi + 1) * (1.0f / ZB) - pz);
    bd *= 0.9999f;
    if (__any(d2 > bd * bd)) {
        d0 = d1 = d2 = FLT_MAX; i0 = i1 = i2 = 0;
        for (int j = lane; j < NC; j += 32) {
            float4 s = sp[j];
            float ddx = __fsub_rn(px, s.x);
            float ddy = __fsub_rn(py, s.y);
            float ddz = __fsub_rn(pz, s.z);
            float d = __fadd_rn(__fadd_rn(__fmul_rn(ddx, ddx), __fmul_rn(ddy, ddy)),
                                __fmul_rn(ddz, ddz));
            ins3(d, __float_as_int(s.w), d0, d1, d2, i0, i1, i2);
        }
        merge32(d0, d1, d2, i0, i1, i2);
    }
    float w0 = 1.0f / (d0 + 1e-16f);
    float w1 = 1.0f / (d1 + 1e-16f);
    float w2 = 1.0f / (d2 + 1e-16f);
    float inv = 1.0f / (w0 + w1 + w2);
    w0 *= inv; w1 *= inv; w2 *= inv;
    if (lane == 0) {
        size_t o = ((size_t)b * NF + node) * 3;
        idx[o] = i0; idx[o + 1] = i1; idx[o + 2] = i2;
        wn[o] = w0; wn[o + 1] = w1; wn[o + 2] = w2;
    }
    const float* xb = xc + (size_t)b * NC * CIN;
    float4 a = *(const float4*)&xb[(size_t)i0 * CIN + lane * 4];
    float4 bb = *(const float4*)&xb[(size_t)i1 * CIN + lane * 4];
    float4 cc = *(const float4*)&xb[(size_t)i2 * CIN + lane * 4];
    ushort4 u;
    u.x = f2b(w0 * a.x + w1 * bb.x + w2 * cc.x);
    u.y = f2b(w0 * a.y + w1 * bb.y + w2 * cc.y);
    u.z = f2b(w0 * a.z + w1 * bb.z + w2 * cc.z);
    u.w = f2b(w0 * a.w + w1 * bb.w + w2 * cc.w);
    *(ushort4*)&xup[((size_t)b * NF + node) * CIN + lane * 4] = u;
}

// ---------------------------------------------------------------- MFMA staged-segment inner loop (128-row tile)
__device__ __forceinline__ void mfma_seg(const ushort* __restrict__ Ab, int K, int m0,
                                         const ushort* __restrict__ Wt, int ldW, int wcol0,
                                         ushort* As, ushort* Wsm,
                                         int t, int wr, int wc, int fr, int fq,
                                         f32x4 (&acc)[4][4]) {
    const int sr = t >> 2, sk = (t & 3) * 8;
    for (int k0 = 0; k0 < K; k0 += 32) {
        #pragma unroll
        for (int p = 0; p < 2; ++p) {
            int r = sr + p * 64;
            *reinterpret_cast<int4*>(&As[r * LDK + sk]) =
                *reinterpret_cast<const int4*>(&Ab[(size_t)(m0 + r) * K + k0 + sk]);
            *reinterpret_cast<int4*>(&Wsm[r * LDK + sk]) =
                *reinterpret_cast<const int4*>(&Wt[(size_t)r * ldW + wcol0 + k0 + sk]);
        }
        __syncthreads();
        short8v af[4], wf[4];
        #pragma unroll
        for (int m = 0; m < 4; ++m)
            af[m] = *reinterpret_cast<const short8v*>(&As[(wr * 64 + m * 16 + fr) * LDK + fq * 8]);
        #pragma unroll
        for (int n = 0; n < 4; ++n)
            wf[n] = *reinterpret_cast<const short8v*>(&Wsm[(wc * 64 + n * 16 + fr) * LDK + fq * 8]);
        #pragma unroll
        for (int m = 0; m < 4; ++m)
            #pragma unroll
            for (int n = 0; n < 4; ++n)
                acc[m][n] = __builtin_amdgcn_mfma_f32_16x16x32_bf16(af[m], wf[n], acc[m][n], 0, 0, 0);
        __syncthreads();
    }
}

// ---------------------------------------------------------------- coarse PQ GEMM (standalone): M=2048, N=128 (P|Q), K=128
__global__ __launch_bounds__(256) void cpq_kernel(const ushort* __restrict__ xb16,
                                                  const ushort* __restrict__ W1eT,
                                                  ushort* __restrict__ PQc) {
    __shared__ ushort As[128 * LDK];
    __shared__ ushort Wsm[128 * LDK];
    const int bx = blockIdx.x;
    const int tid = threadIdx.x;
    const int b = bx >> 4, m0 = (bx & 15) * 128;
    const int lane = tid & 63, wid = tid >> 6;
    const int wr = wid >> 1, wc = wid & 1;
    const int fr = lane & 15, fq = lane >> 4;
    f32x4 acc[4][4];
    #pragma unroll
    for (int m = 0; m < 4; ++m)
        #pragma unroll
        for (int n = 0; n < 4; ++n) acc[m][n] = (f32x4){0.f, 0.f, 0.f, 0.f};
    mfma_seg(xb16 + (size_t)b * NC * 128, 128, m0, W1eT, 128, 0,
             As, Wsm, tid, wr, wc, fr, fq, acc);
    ushort* Cb = PQc + (size_t)b * NC * 128;
    #pragma unroll
    for (int m = 0; m < 4; ++m)
        #pragma unroll
        for (int n = 0; n < 4; ++n) {
            int col = wc * 64 + n * 16 + fr;
            #pragma unroll
            for (int r = 0; r < 4; ++r) {
                int row = m0 + wr * 64 + m * 16 + fq * 4 + r;
                Cb[(size_t)row * 128 + col] = f2b(acc[m][n][r]);
            }
        }
}

// ---------------------------------------------------------------- coarse agg (standalone, bf16, no LDS -> full occupancy)
__global__ __launch_bounds__(256) void aggc_b16(const ushort* __restrict__ PQc,
                                                const float* __restrict__ b1e,
                                                const int* __restrict__ offC,
                                                const int* __restrict__ cntC,
                                                const int* __restrict__ csrC,
                                                ushort* __restrict__ aggC) {
    const int b = blockIdx.y;
    const int dst = blockIdx.x * 4 + (threadIdx.x >> 6);
    const int lane = threadIdx.x & 63;
    const ushort* Pb = PQc + (size_t)b * NC * 128;
    const int start = offC[b * NC + dst];
    const int cnt = cntC[b * NC + dst];
    const int* sl = csrC + (size_t)b * EC + start;
    const float q = b2f(Pb[(size_t)dst * 128 + 64 + lane]) + b1e[lane];
    float a = 0.0f;
    for (int i = 0; i < cnt; ++i) {
        int src = sl[i];
        float m = b2f(Pb[(size_t)src * 128 + lane]) + q; m = m > 0.0f ? m : 0.01f * m;
        a += m;
    }
    aggC[(size_t)b * NC * 64 + (size_t)dst * 64 + lane] = f2b(a);
}

// ---------------------------------------------------------------- coarse x1 node GEMM (standalone, 256-row tile, N=64)
__global__ __launch_bounds__(256) void x1_kernel(const ushort* __restrict__ xb16,
                                                 const ushort* __restrict__ aggC,
                                                 const ushort* __restrict__ W1nT,
                                                 const float* __restrict__ b1n,
                                                 ushort* __restrict__ x1b) {
    __shared__ ushort As[256 * LDK];
    __shared__ ushort Wsm[64 * LDK];
    const int bx = blockIdx.x;
    const int tid = threadIdx.x;
    const int b = bx >> 3, m0 = (bx & 7) * 256;
    const int lane = tid & 63, wr = tid >> 6;
    const int fr = lane & 15, fq = lane >> 4;
    const int sr = tid >> 2, sk = (tid & 3) * 8;
    f32x4 acc[4][4];
    #pragma unroll
    for (int m = 0; m < 4; ++m)
        #pragma unroll
        for (int n = 0; n < 4; ++n) acc[m][n] = (f32x4){0.f, 0.f, 0.f, 0.f};
    // segment 1: A = xb16, K=128, W cols 0-127
    const ushort* A1 = xb16 + (size_t)b * NC * 128;
    for (int k0 = 0; k0 < 128; k0 += 32) {
        #pragma unroll
        for (int p = 0; p < 4; ++p) {
            int r = sr + p * 64;
            *reinterpret_cast<int4*>(&As[r * LDK + sk]) =
                *reinterpret_cast<const int4*>(&A1[(size_t)(m0 + r) * 128 + k0 + sk]);
        }
        *reinterpret_cast<int4*>(&Wsm[sr * LDK + sk]) =
            *reinterpret_cast<const int4*>(&W1nT[(size_t)sr * 192 + k0 + sk]);
        __syncthreads();
        short8v af[4], wf[4];
        #pragma unroll
        for (int m = 0; m < 4; ++m)
            af[m] = *reinterpret_cast<const short8v*>(&As[(wr * 64 + m * 16 + fr) * LDK + fq * 8]);
        #pragma unroll
        for (int n = 0; n < 4; ++n)
            wf[n] = *reinterpret_cast<const short8v*>(&Wsm[(n * 16 + fr) * LDK + fq * 8]);
        #pragma unroll
        for (int m = 0; m < 4; ++m)
            #pragma unroll
            for (int n = 0; n < 4; ++n)
                acc[m][n] = __builtin_amdgcn_mfma_f32_16x16x32_bf16(af[m], wf[n], acc[m][n], 0, 0, 0);
        __syncthreads();
    }
    // segment 2: A = aggC, K=64, W cols 128-191
    const ushort* A2 = aggC + (size_t)b * NC * 64;
    for (int k0 = 0; k0 < 64; k0 += 32) {
        #pragma unroll
        for (int p = 0; p < 4; ++p) {
            int r = sr + p * 64;
            *reinterpret_cast<int4*>(&As[r * LDK + sk]) =
                *reinterpret_cast<const int4*>(&A2[(size_t)(m0 + r) * 64 + k0 + sk]);
        }
        *reinterpret_cast<int4*>(&Wsm[sr * LDK + sk]) =
            *reinterpret_cast<const int4*>(&W1nT[(size_t)sr * 192 + 128 + k0 + sk]);
        __syncthreads();
        short8v af[4], wf[4];
        #pragma unroll
        for (int m = 0; m < 4; ++m)
            af[m] = *reinterpret_cast<const short8v*>(&As[(wr * 64 + m * 16 + fr) * LDK + fq * 8]);
        #pragma unroll
        for (int n = 0; n < 4; ++n)
            wf[n] = *reinterpret_cast<const short8v*>(&Wsm[(n * 16 + fr) * LDK + fq * 8]);
        #pragma unroll
        for (int m = 0; m < 4; ++m)
            #pragma unroll
            for (int n = 0; n < 4; ++n)
                acc[m][n] = __builtin_amdgcn_mfma_f32_16x16x32_bf16(af[m], wf[n], acc[m][n], 0, 0, 0);
        __syncthreads();
    }
    ushort* Cb = x1b + (size_t)b * NC * 64;
    #pragma unroll
    for (int m = 0; m < 4; ++m)
        #pragma unroll
        for (int n = 0; n < 4; ++n) {
            int col = n * 16 + fr;
            float bv = b1n[col];
            #pragma unroll
            for (int r = 0; r < 4; ++r) {
                int row = m0 + wr * 64 + m * 16 + fq * 4 + r;
                float v = acc[m][n][r] + bv;
                v = v > 0.0f ? v : 0.01f * v;
                Cb[(size_t)row * 64 + col] = f2b(v);
            }
        }
}

// ---------------------------------------------------------------- x1_up interp (bf16 source, C=64: 16 lanes/node)
__global__ __launch_bounds__(256) void interp_x1(const ushort* __restrict__ x1b,
                                                 const int* __restrict__ idx,
                                                 const float* __restrict__ wn,
                                                 ushort* __restrict__ out) {
    const int b = blockIdx.y;
    const int node = blockIdx.x * 16 + (threadIdx.x >> 4);
    const int lane = threadIdx.x & 15;
    size_t o = ((size_t)b * NF + node) * 3;
    int i0 = idx[o], i1 = idx[o + 1], i2 = idx[o + 2];
    float w0 = wn[o], w1 = wn[o + 1], w2 = wn[o + 2];
    const ushort* xb = x1b + (size_t)b * NC * 64;
    ushort4 a = *(const ushort4*)&xb[(size_t)i0 * 64 + lane * 4];
    ushort4 bb = *(const ushort4*)&xb[(size_t)i1 * 64 + lane * 4];
    ushort4 cc = *(const ushort4*)&xb[(size_t)i2 * 64 + lane * 4];
    ushort4 u;
    u.x = f2b(w0 * b2f(a.x) + w1 * b2f(bb.x) + w2 * b2f(cc.x));
    u.y = f2b(w0 * b2f(a.y) + w1 * b2f(bb.y) + w2 * b2f(cc.y));
    u.z = f2b(w0 * b2f(a.z) + w1 * b2f(bb.z) + w2 * b2f(cc.z));
    u.w = f2b(w0 * b2f(a.w) + w1 * b2f(bb.w) + w2 * b2f(cc.w));
    *(ushort4*)&out[((size_t)b * NF + node) * 64 + lane * 4] = u;
}

// ---------------------------------------------------------------- both branches' PQ GEMMs in one launch (R10-proven)
__global__ __launch_bounds__(256) void mfma_pq_both(
    const ushort* __restrict__ x1upb, const ushort* __restrict__ xupb,
    const ushort* __restrict__ W2eT, const ushort* __restrict__ WseT,
    ushort* __restrict__ P2, ushort* __restrict__ Q2,
    ushort* __restrict__ PS, ushort* __restrict__ QS) {
    __shared__ ushort As[128 * LDK];
    __shared__ ushort Wsm[128 * LDK];
    const int t = threadIdx.x;
    const int lane = t & 63, wid = t >> 6;
    const int wr = wid >> 1, wc = wid & 1;
    const int fr = lane & 15, fq = lane >> 4;
    const int z = blockIdx.z;
    const int b = z >> 2, sel = z & 3;
    const int br = sel >> 1, pq = sel & 1;
    const int m0 = blockIdx.x * 128;
    f32x4 acc[4][4];
    #pragma unroll
    for (int m = 0; m < 4; ++m)
        #pragma unroll
        for (int n = 0; n < 4; ++n) acc[m][n] = (f32x4){0.f, 0.f, 0.f, 0.f};
    ushort* outp;
    if (br == 0) {
        mfma_seg(x1upb + (size_t)b * NF * 64, 64, m0, W2eT, 128, pq * 64,
                 As, Wsm, t, wr, wc, fr, fq, acc);
        outp = pq ? Q2 : P2;
    } else {
        mfma_seg(xupb + (size_t)b * NF * 128, 128, m0, WseT, 256, pq * 128,
                 As, Wsm, t, wr, wc, fr, fq, acc);
        outp = pq ? QS : PS;
    }
    ushort* Cb = outp + (size_t)b * NF * 128;
    #pragma unroll
    for (int m = 0; m < 4; ++m)
        #pragma unroll
        for (int n = 0; n < 4; ++n) {
            int col = wc * 64 + n * 16 + fr;
            #pragma unroll
            for (int r = 0; r < 4; ++r) {
                int row = m0 + wr * 64 + m * 16 + fq * 4 + r;
                Cb[(size_t)row * 128 + col] = f2b(acc[m][n][r]);
            }
        }
}

// ---------------------------------------------------------------- fine agg, XCD-paired (R10-proven)
__global__ __launch_bounds__(256) void agg_csr_b16(const ushort* __restrict__ P2,
                                                   const ushort* __restrict__ Q2,
                                                   const float* __restrict__ b2,
                                                   const ushort* __restrict__ PS,
                                                   const ushort* __restrict__ QS,
                                                   const float* __restrict__ bS,
                                                   const int* __restrict__ offs,
                                                   const int* __restrict__ counts,
                                                   const int* __restrict__ csr_src,
                                                   ushort* __restrict__ agg2,
                                                   ushort* __restrict__ aggS) {
    const int lin = blockIdx.x;
    const int pair = lin & 7;               // consecutive blocks round-robin XCDs
    const int b = pair >> 1, br = pair & 1;
    const int chunk = lin >> 3;
    const ushort* P = br ? PS : P2;
    const ushort* Q = br ? QS : Q2;
    const float* bias = br ? bS : b2;
    ushort* agg = br ? aggS : agg2;
    const int dst = chunk * 4 + (threadIdx.x >> 6);
    const int lane = threadIdx.x & 63;
    const ushort* Pb = P + (size_t)b * NF * 128;
    const ushort* Qb = Q + (size_t)b * NF * 128;
    const int start = offs[b * NF + dst];
    const int cnt = counts[b * NF + dst];
    const int* sl = csr_src + (size_t)b * EF + start;
    const int c0 = lane, c1 = lane + 64;
    const float q0 = b2f(Qb[(size_t)dst * 128 + c0]) + bias[c0];
    const float q1 = b2f(Qb[(size_t)dst * 128 + c1]) + bias[c1];
    float a0 = 0.0f, a1 = 0.0f;
    int i = 0;
    for (; i + 4 <= cnt; i += 4) {
        int s0 = sl[i], s1 = sl[i + 1], s2 = sl[i + 2], s3 = sl[i + 3];
        ushort p00 = Pb[(size_t)s0 * 128 + c0], p01 = Pb[(size_t)s0 * 128 + c1];
        ushort p10 = Pb[(size_t)s1 * 128 + c0], p11 = Pb[(size_t)s1 * 128 + c1];
        ushort p20 = Pb[(size_t)s2 * 128 + c0], p21 = Pb[(size_t)s2 * 128 + c1];
        ushort p30 = Pb[(size_t)s3 * 128 + c0], p31 = Pb[(size_t)s3 * 128 + c1];
        float m;
        m = b2f(p00) + q0; m = m > 0.0f ? m : 0.01f * m; a0 += m;
        m = b2f(p01) + q1; m = m > 0.0f ? m : 0.01f * m; a1 += m;
        m = b2f(p10) + q0; m = m > 0.0f ? m : 0.01f * m; a0 += m;
        m = b2f(p11) + q1; m = m > 0.0f ? m : 0.01f * m; a1 += m;
        m = b2f(p20) + q0; m = m > 0.0f ? m : 0.01f * m; a0 += m;
        m = b2f(p21) + q1; m = m > 0.0f ? m : 0.01f * m; a1 += m;
        m = b2f(p30) + q0; m = m > 0.0f ? m : 0.01f * m; a0 += m;
        m = b2f(p31) + q1; m = m > 0.0f ? m : 0.01f * m; a1 += m;
    }
    for (; i < cnt; ++i) {
        int src = sl[i];
        float m0 = b2f(Pb[(size_t)src * 128 + c0]) + q0; m0 = m0 > 0.0f ? m0 : 0.01f * m0;
        float m1 = b2f(Pb[(size_t)src * 128 + c1]) + q1; m1 = m1 > 0.0f ? m1 : 0.01f * m1;
        a0 += m0; a1 += m1;
    }
    __builtin_nontemporal_store(f2b(a0), &agg[(size_t)b * NF * 128 + (size_t)dst * 128 + c0]);
    __builtin_nontemporal_store(f2b(a1), &agg[(size_t)b * NF * 128 + (size_t)dst * 128 + c1]);
}

// ---------------------------------------------------------------- fused dual-branch node GEMM + BN stats (R10-proven)
__global__ __launch_bounds__(256) void mfma_node2(
    const ushort* __restrict__ A1, const ushort* __restrict__ A2,
    const ushort* __restrict__ Wt1, const float* __restrict__ bias1,
    const ushort* __restrict__ A3, const ushort* __restrict__ A4,
    const ushort* __restrict__ Wt2, const float* __restrict__ bias2,
    float* __restrict__ y, float* __restrict__ stats) {
    __shared__ ushort As[128 * LDK];
    __shared__ ushort Wsm[128 * LDK];
    const int t = threadIdx.x;
    const int lane = t & 63, wid = t >> 6;
    const int wr = wid >> 1, wc = wid & 1;
    const int fr = lane & 15, fq = lane >> 4;
    const int b = blockIdx.z;
    const int m0 = blockIdx.x * 128;
    f32x4 acc1[4][4], acc2[4][4];
    #pragma unroll
    for (int m = 0; m < 4; ++m)
        #pragma unroll
        for (int n = 0; n < 4; ++n) {
            acc1[m][n] = (f32x4){0.f, 0.f, 0.f, 0.f};
            acc2[m][n] = (f32x4){0.f, 0.f, 0.f, 0.f};
        }
    mfma_seg(A1 + (size_t)b * NF * 64,  64,  m0, Wt1, 192, 0,   As, Wsm, t, wr, wc, fr, fq, acc1);
    mfma_seg(A2 + (size_t)b * NF * 128, 128, m0, Wt1, 192, 64,  As, Wsm, t, wr, wc, fr, fq, acc1);
    mfma_seg(A3 + (size_t)b * NF * 128, 128, m0, Wt2, 256, 0,   As, Wsm, t, wr, wc, fr, fq, acc2);
    mfma_seg(A4 + (size_t)b * NF * 128, 128, m0, Wt2, 256, 128, As, Wsm, t, wr, wc, fr, fq, acc2);
    float* Yb = y + (size_t)b * NF * 128;
    float lsum[4] = {0.f, 0.f, 0.f, 0.f}, lsq[4] = {0.f, 0.f, 0.f, 0.f};
    #pragma unroll
    for (int m = 0; m < 4; ++m)
        #pragma unroll
        for (int n = 0; n < 4; ++n) {
            int col = wc * 64 + n * 16 + fr;
            float bv1 = bias1[col], bv2 = bias2[col];
            #pragma unroll
            for (int r = 0; r < 4; ++r) {
                int row = m0 + wr * 64 + m * 16 + fq * 4 + r;
                float v1 = acc1[m][n][r] + bv1; v1 = v1 > 0.0f ? v1 : 0.01f * v1;
                float v2 = acc2[m][n][r] + bv2; v2 = v2 > 0.0f ? v2 : 0.01f * v2;
                float v = v1 + v2;
                Yb[(size_t)row * 128 + col] = v;
                lsum[n] += v;
                lsq[n] = fmaf(v, v, lsq[n]);
            }
        }
    __syncthreads();
    float* ssum = reinterpret_cast<float*>(As);
    float* ssq  = ssum + 128;
    if (t < 128) { ssum[t] = 0.0f; ssq[t] = 0.0f; }
    __syncthreads();
    #pragma unroll
    for (int n = 0; n < 4; ++n) {
        int col = wc * 64 + n * 16 + fr;
        atomicAdd(&ssum[col], lsum[n]);
        atomicAdd(&ssq[col], lsq[n]);
    }
    __syncthreads();
    if (t < 128) {
        atomicAdd(&stats[t], ssum[t]);
        atomicAdd(&stats[128 + t], ssq[t]);
    }
}

// ---------------------------------------------------------------- batch-norm finalize + wf via inv map
__global__ __launch_bounds__(256) void bn_final(float* __restrict__ xs,
                                                const float* __restrict__ stats,
                                                const float* __restrict__ gamma,
                                                const float* __restrict__ beta,
                                                float* __restrict__ wf,
                                                const float* __restrict__ wts,
                                                const int* __restrict__ inv) {
    const long i = (long)blockIdx.x * 256 + threadIdx.x;   // float4 index
    const long g4 = i * 4;
    const int c = (int)(g4 & (COUT - 1));
    const float invN = 1.0f / (float)(B * NF);
    float4 v = *(float4*)&xs[g4];
    float vv[4] = {v.x, v.y, v.z, v.w};
    #pragma unroll
    for (int k = 0; k < 4; ++k) {
        int ck = c + k;
        float mu = stats[ck] * invN;
        float var = stats[COUT + ck] * invN - mu * mu;
        float t = (vv[k] - mu) * rsqrtf(var + 1e-5f) * gamma[ck] + beta[ck];
        vv[k] = t > 0.0f ? t : 0.01f * t;
    }
    *(float4*)&xs[g4] = make_float4(vv[0], vv[1], vv[2], vv[3]);
    if (i < (long)B * NF) {
        int iv = inv[i];
        wf[i] = (iv >= 0) ? wts[iv] : 0.0f;
    }
}

extern "C" void kernel_launch(void* const* d_in, const int* in_sizes, int n_in,
                              void* d_out, int out_size, void* d_ws, size_t ws_size,
                              hipStream_t stream) {
    const float* x    = (const float*)d_in[0];
    const float* wts  = (const float*)d_in[1];
    const float* pos  = (const float*)d_in[2];
    const float* W1e  = (const float*)d_in[3];
    const float* b1e  = (const float*)d_in[4];
    const float* W1n  = (const float*)d_in[5];
    const float* b1n  = (const float*)d_in[6];
    const float* W2e  = (const float*)d_in[7];
    const float* b2e  = (const float*)d_in[8];
    const float* W2n  = (const float*)d_in[9];
    const float* b2n  = (const float*)d_in[10];
    const float* Wse  = (const float*)d_in[11];
    const float* bse  = (const float*)d_in[12];
    const float* Wsn  = (const float*)d_in[13];
    const float* bsn  = (const float*)d_in[14];
    const float* gamma= (const float*)d_in[15];
    const float* beta = (const float*)d_in[16];
    const int*   mask = (const int*)d_in[17];
    const int*   ec   = (const int*)d_in[18];
    const int*   ef   = (const int*)d_in[19];

    float* ws = (float*)d_ws;
    // ---- f32 region
    int*    idxb  = (int*)ws;                              // B*NF*3
    float*  wnb   = ws + 98304;                            // B*NF*3
    float4* sposg = (float4*)(ws + 196608);                // B*NC float4 (z-sorted)
    float*  stats = ws + 196608 + 32768;                   // 256 (contiguous with counts)
    // ---- int region (stats+counts contiguous for single memset)
    int* cntC  = (int*)(stats + 256);                      // B*NC
    int* cntF  = cntC + B * NC;                            // B*NF
    int* cntZ  = cntF + B * NF;                            // B*ZB
    int* offC  = cntZ + B * ZB;                            // B*NC
    int* curC  = offC + B * NC;
    int* offF  = curC + B * NC;                            // B*NF
    int* curF  = offF + B * NF;
    int* offZ  = curF + B * NF;                            // B*(ZB+1)
    int* curZ  = offZ + B * (ZB + 1);
    int* csrC  = curZ + B * (ZB + 1);                      // B*EC
    int* csrF  = csrC + B * EC;                            // B*EF
    int* invm  = csrF + B * EF;                            // B*NF
    // ---- bf16 region
    size_t foff = (size_t)(invm + (size_t)B * NF - (int*)ws);
    foff = (foff + 7) & ~(size_t)7;
    ushort* xupb  = (ushort*)(ws + foff);                  // B*NF*128
    ushort* x1upb = xupb  + (size_t)B * NF * 128;          // B*NF*64
    ushort* P2b   = x1upb + (size_t)B * NF * 64;           // B*NF*128
    ushort* Q2b   = P2b   + (size_t)B * NF * 128;          // B*NF*128
    ushort* PSb   = Q2b   + (size_t)B * NF * 128;          // B*NF*128
    ushort* QSb   = PSb   + (size_t)B * NF * 128;          // B*NF*128
    ushort* agg2b = QSb   + (size_t)B * NF * 128;          // B*NF*128
    ushort* aggSb = agg2b + (size_t)B * NF * 128;          // B*NF*128
    ushort* xb16  = aggSb + (size_t)B * NF * 128;          // B*NC*128
    ushort* PQc   = xb16  + (size_t)B * NC * 128;          // B*NC*128
    ushort* aggCb = PQc   + (size_t)B * NC * 128;          // B*NC*64
    ushort* x1b   = aggCb + (size_t)B * NC * 64;           // B*NC*64
    ushort* W2eT  = x1b   + (size_t)B * NC * 64;           // 128*128
    ushort* W2nT  = W2eT  + 128 * 128;                     // 128*192
    ushort* WseT  = W2nT  + 128 * 192;                     // 128*256
    ushort* WsnT  = WseT  + 128 * 256;                     // 128*256
    ushort* W1eT  = WsnT  + 128 * 256;                     // 128*128
    ushort* W1nT  = W1eT  + 128 * 128;                     // 64*192

    float* y  = (float*)d_out;                             // B*NF*128
    float* wf = y + (size_t)B * NF * COUT;                 // B*NF

    // ---- prep
    hipMemsetAsync(stats, 0, 256 * 4 + (size_t)B * (NC + NF + ZB) * 4, stream);
    count_all<<<dim3(EF / 256, B, 6), 256, 0, stream>>>(
        ec, ef, mask, pos, cntC, cntF, cntZ, invm,
        W2e, W2n, Wse, Wsn, W2eT, W2nT, WseT, WsnT,
        W1e, W1n, W1eT, W1nT, x, xb16);
    scan_all<<<dim3(3 * B), 1024, 0, stream>>>(cntC, offC, curC, cntF, offF, curF, cntZ, offZ, curZ);
    fill_all<<<dim3(EF / 256, B, 3), 256, 0, stream>>>(ec, ef, mask, pos, curC, curF, curZ,
                                                       csrC, csrF, sposg, invm);

    // ---- fused knn + x_up interpolation
    knn_interp<<<dim3(NF / 8, B), 256, 0, stream>>>(pos, sposg, offZ, x, idxb, wnb, xupb);

    // ---- coarse path (bf16 MFMA, standalone kernels)
    cpq_kernel<<<dim3(B * NC / 128), 256, 0, stream>>>(xb16, W1eT, PQc);
    aggc_b16<<<dim3(NC / 4, B), 256, 0, stream>>>(PQc, b1e, offC, cntC, csrC, aggCb);
    x1_kernel<<<dim3(B * NC / 256), 256, 0, stream>>>(xb16, aggCb, W1nT, b1n, x1b);

    // ---- x1_up = interp(x1) (bf16 source)
    interp_x1<<<dim3(NF / 16, B), 256, 0, stream>>>(x1b, idxb, wnb, x1upb);

    // ---- both branches' edge PQ GEMMs, then both agg passes (XCD-paired 1-D grid)
    mfma_pq_both<<<dim3(NF / 128, 1, B * 4), 256, 0, stream>>>(
        x1upb, xupb, W2eT, WseT, P2b, Q2b, PSb, QSb);
    agg_csr_b16<<<dim3((NF / 4) * B * 2), 256, 0, stream>>>(
        P2b, Q2b, b2e, PSb, QSb, bse, offF, cntF, csrF, agg2b, aggSb);

    // ---- fused dual-branch node GEMM + BN stats -> y
    mfma_node2<<<dim3(NF / 128, 1, B), 256, 0, stream>>>(
        x1upb, agg2b, W2nT, b2n, xupb, aggSb, WsnT, bsn, y, stats);

    // ---- batch norm finalize + lrelu + direct w_fine write
    bn_final<<<dim3((long)B * NF * COUT / 1024), 256, 0, stream>>>(y, stats, gamma, beta, wf, wts, invm);
}